// Round 17
// baseline (563.949 us; speedup 1.0000x reference)
//
#include <hip/hip_runtime.h>
#include <hip/hip_bf16.h>

typedef short s8v  __attribute__((ext_vector_type(8)));
typedef float f32x4 __attribute__((ext_vector_type(4)));
typedef unsigned int u32;
typedef u32 u32x4 __attribute__((ext_vector_type(4)));

#define NSLOT 31
#define NBIAS 17

// ---------- bf16 helpers (RNE) ----------
__device__ __forceinline__ unsigned short b16hi(float v) {
  unsigned int u = __float_as_uint(v);
  return (unsigned short)((u + 0x7FFFu + ((u >> 16) & 1u)) >> 16);
}
__device__ __forceinline__ float b16tof(unsigned short h) {
  return __uint_as_float(((unsigned int)h) << 16);
}
__device__ __forceinline__ unsigned short lobits(float w) {
  return b16hi(w - b16tof(b16hi(w)));
}
__device__ __forceinline__ float sp_stable(float v) {
  float ax = __builtin_fabsf(v);
  float e  = __expf(-ax);
  return fmaxf(v, 0.0f) + __logf(1.0f + e);
}

// =====================================================================
// PREP (R12 layout, verified): A-frags for D = W . act^T, biases zeroed
// out of the weight slots; exact-f32 bias table consumed as MFMA C-init.
// lane l: m = l&15, k = 4*(l>>4)+{0..3} (dw0,1) and 16+4*(l>>4)+{0..3} (dw2,3)
// =====================================================================
struct P {
  const float *yW0,*yWs,*yb,*zW0,*zWs,*zb,*tW0,*tWs,*tb;
  const float *x0W,*x0b,*y0W,*y0b,*z0W,*z0b,*t0W,*t0b;
  const float *xWs,*xb,*xsW,*xsb,*xyW,*xyb,*xzW,*xzb,*xtW,*xtb,*fW,*fb;
};

__device__ unsigned short pat15(const float* W, int k, int j, int sp) {
  if (k < 15)           { float v = W[j*15+k];      return b16hi(sp ? sp_stable(v) : v); }
  if (k >= 16 && k < 31){ float v = W[j*15+(k-16)]; return lobits(sp ? sp_stable(v) : v); }
  return 0;
}

__device__ unsigned short wA(int s, int k, int j, const P& p) {
  if (j > 14) return 0;
  if (s == 0) {
    if (k < 8)   return b16hi(sp_stable(p.yW0[j*8+k]));
    if (k < 16)  return lobits(sp_stable(p.yW0[j*8+(k-8)]));
    return 0;
  }
  if (s <= 3)  return pat15(p.yWs + (s-1)*225, k, j, 1);
  if (s == 4) {
    if (k < 8)   return b16hi(p.zW0[j*8+k]);
    if (k < 16)  return lobits(p.zW0[j*8+(k-8)]);
    return 0;
  }
  if (s <= 7)  return pat15(p.zWs + (s-5)*225, k, j, 0);
  if (s == 8) {
    if (k < 4)   return b16hi(sp_stable(p.tW0[j*4+k]));
    if (k < 8)   return lobits(sp_stable(p.tW0[j*4+(k-4)]));
    return 0;
  }
  if (s <= 11) return pat15(p.tWs + (s-9)*225, k, j, 1);
  if (s == 12) {
    if (k < 16) return b16hi(p.x0W[j*16+k]);
    return lobits(p.x0W[j*16+(k-16)]);
  }
  if (s == 13) {
    if (k < 8)  return b16hi(sp_stable(p.y0W[j*8+k]));
    if (k < 16) return b16hi(p.z0W[j*8+(k-8)]);
    if (k < 24) return lobits(sp_stable(p.y0W[j*8+(k-16)]));
    return lobits(p.z0W[j*8+(k-24)]);
  }
  if (s == 14) {
    if (k < 4)  return b16hi(sp_stable(p.t0W[j*4+k]));
    if (k < 8)  return lobits(sp_stable(p.t0W[j*4+(k-4)]));
    return 0;
  }
  if (s <= 29) {
    int i = (s-15)/5, r = (s-15)%5;
    if (r == 0) return pat15(p.xWs + i*225, k, j, 1);
    if (r == 1) {
      const float* W = p.xsW + i*240;
      if (k < 16) return b16hi(W[j*16+k]);
      return lobits(W[j*16+(k-16)]);
    }
    if (r == 2) return pat15(p.xyW + i*225, k, j, 1);
    if (r == 3) return pat15(p.xzW + i*225, k, j, 0);
    return pat15(p.xtW + i*225, k, j, 1);
  }
  return pat15(p.fW, k, j, 0);   // s == 30
}

__global__ void prep_kernel(P p, u32* Abuf, float* biasb) {
  const int tid = blockIdx.x * blockDim.x + threadIdx.x;
  const int str = gridDim.x * blockDim.x;
  for (int idx = tid; idx < NSLOT*256; idx += str) {
    int s = idx >> 8, rem = idx & 255, l = rem >> 2, d = rem & 3;
    int g = l >> 4, j = l & 15;
    int kb = (d < 2) ? (4*g + 2*d) : (16 + 4*g + 2*(d-2));
    u32 v0 = wA(s, kb,   j, p);
    u32 v1 = wA(s, kb+1, j, p);
    Abuf[idx] = v0 | (v1 << 16);
  }
  for (int idx = tid; idx < NBIAS*16; idx += str) {
    int b = idx >> 4, n = idx & 15;
    float v = 0.f;
    if (n < 15) {
      if (b < 4)        v = p.yb[b*15 + n];
      else if (b < 8)   v = p.zb[(b-4)*15 + n];
      else if (b < 12)  v = p.tb[(b-8)*15 + n];
      else if (b == 12) v = p.x0b[n] + p.y0b[n] + p.z0b[n] + p.t0b[n];
      else if (b < 16)  { int i = b - 13;
        v = p.xb[i*15+n] + p.xsb[i*15+n] + p.xyb[i*15+n]
          + p.xzb[i*15+n] + p.xtb[i*15+n]; }
      else              v = p.fb[n];
    }
    biasb[idx] = v;
  }
}

// =====================================================================
// MAIN: (512,6) geometry — 8 waves share one weight image, 85-reg
// budget — with TWO straight-line tile bodies per wave and NO schedule
// barrier between them: the compiler may interleave the bodies to fill
// dependency stalls (R16 lesson: sched_barrier(0) blocked this and
// VALUBusy dropped).  Post-diet body = 28 VGPR (R16-measured), so the
// interleaved live set ~60-75 fits 85.  Each tile gets its own olds
// half (no same-wave LDS WAR hazard under reordering).
// Anti-spill ledger: no loops; FETCH_SIZE is the spill sentinel.
// =====================================================================
union FragU { u32x4 u; s8v s; };
__device__ __forceinline__ s8v mkfrag(u32 a, u32 b, u32 c, u32 d) {
  FragU f; f.u = u32x4{a, b, c, d}; return f.s;
}
__device__ __forceinline__ u32 pk(float lo, float hi) {
  union { __hip_bfloat162 h; u32 u; } cv;
  cv.h = __float22bfloat162_rn(float2{lo, hi});
  return cv.u;
}
__device__ __forceinline__ float lo16f(u32 u) { return __uint_as_float(u << 16); }
__device__ __forceinline__ float hi16f(u32 u) { return __uint_as_float(u & 0xFFFF0000u); }

#define MFMA(A,B,C) __builtin_amdgcn_mfma_f32_16x16x32_bf16((A),(B),(C),0,0,0)

__device__ __forceinline__ void act_sp(f32x4 a, u32& h0, u32& h1,
                                       u32& l0, u32& l1) {
  const f32x4 z4 = {0.f, 0.f, 0.f, 0.f};
  f32x4 ax = __builtin_elementwise_abs(a);
  f32x4 mx = __builtin_elementwise_max(a, z4);
  f32x4 nt = ax * -1.442695041f;
  f32x4 e;
  e[0] = __builtin_amdgcn_exp2f(nt[0]); e[1] = __builtin_amdgcn_exp2f(nt[1]);
  e[2] = __builtin_amdgcn_exp2f(nt[2]); e[3] = __builtin_amdgcn_exp2f(nt[3]);
  f32x4 op = e + 1.0f;
  f32x4 lg;
  lg[0] = __builtin_amdgcn_logf(op[0]); lg[1] = __builtin_amdgcn_logf(op[1]);
  lg[2] = __builtin_amdgcn_logf(op[2]); lg[3] = __builtin_amdgcn_logf(op[3]);
  f32x4 v = lg * 0.6931471806f + mx;
  h0 = pk(v[0], v[1]);
  h1 = pk(v[2], v[3]);
  l0 = pk(v[0] - lo16f(h0), v[1] - hi16f(h0));
  l1 = pk(v[2] - lo16f(h1), v[3] - hi16f(h1));
}
__device__ __forceinline__ void act_sig(f32x4 a, u32& d0, u32& d1) {
  f32x4 nt = a * -1.442695041f;
  f32x4 e;
  e[0] = __builtin_amdgcn_exp2f(nt[0]); e[1] = __builtin_amdgcn_exp2f(nt[1]);
  e[2] = __builtin_amdgcn_exp2f(nt[2]); e[3] = __builtin_amdgcn_exp2f(nt[3]);
  f32x4 op = e + 1.0f;
  float r0 = __builtin_amdgcn_rcpf(op[0]), r1 = __builtin_amdgcn_rcpf(op[1]);
  float r2 = __builtin_amdgcn_rcpf(op[2]), r3 = __builtin_amdgcn_rcpf(op[3]);
  d0 = pk(r0, r1);
  d1 = pk(r2, r3);
}

struct Pre { float4 x4, y4, z4, t4; };

__device__ __forceinline__ Pre load_in(const float* x0g, const float* y0g,
                                       const float* z0g, const float* t0g,
                                       int T, int c, int g) {
  Pre p;
  p.x4 = ((const float4*)x0g)[(size_t)(T*16 + c)*4 + g];
  p.y4 = ((const float4*)y0g)[(size_t)(T*16 + c)*2 + (g & 1)];
  p.z4 = ((const float4*)z0g)[(size_t)(T*16 + c)*2 + (g & 1)];
  p.t4 = ((const float4*)t0g)[(size_t)(T*16 + c)];
  return p;
}

__device__ __forceinline__ void tile_body(const Pre& in, int T,
                                          const char* wbase, const char* bbase,
                                          float* owave, float* outg,
                                          int lane, int g, int c) {
#define AW(s)   (*(const s8v*)(wbase + (s)*1024))
#define BIAS(s) (*(const f32x4*)(bbase + (s)*64))
  // ---- build input B-frags
  u32 dx0 = pk(in.x4.x, in.x4.y), dx1 = pk(in.x4.z, in.x4.w);
  u32 dy0 = pk(in.y4.x, in.y4.y), dy1 = pk(in.y4.z, in.y4.w);
  u32 dz0 = pk(in.z4.x, in.z4.y), dz1 = pk(in.z4.z, in.z4.w);
  u32 dt0 = pk(in.t4.x, in.t4.y), dt1 = pk(in.t4.z, in.t4.w);
  s8v Bx0 = mkfrag(dx0, dx1, dx0, dx1);
  s8v By0 = mkfrag(dy0, dy1, 0u, 0u);
  s8v Bz0 = mkfrag(dz0, dz1, 0u, 0u);
  s8v Bt0 = mkfrag((g < 2) ? dt0 : 0u, (g < 2) ? dt1 : 0u, 0u, 0u);
  u32 syz0 = (g < 2) ? dy0 : dz0, syz1 = (g < 2) ? dy1 : dz1;
  s8v Byz = mkfrag(syz0, syz1, syz0, syz1);

  // ---- towers layer 1 (bias = exact-f32 C-init)
  f32x4 aY = MFMA(AW(0), By0, BIAS(0));
  f32x4 aZ = MFMA(AW(4), Bz0, BIAS(4));
  f32x4 aT = MFMA(AW(8), Bt0, BIAS(8));

  // ---- towers layers 2..4
  u32 yh0, yh1, yl0, yl1, zf0, zf1, tf0, tf1;
#pragma unroll
  for (int l = 0; l < 3; ++l) {
    act_sp(aY, yh0, yh1, yl0, yl1);
    act_sig(aZ, zf0, zf1);
    act_sig(aT, tf0, tf1);
    s8v ay = AW(1+l);
    aY = MFMA(ay, mkfrag(yh0, yh1, yh0, yh1), BIAS(1+l));
    aY = MFMA(ay, mkfrag(yl0, yl1, 0u, 0u), aY);
    aZ = MFMA(AW(5+l), mkfrag(zf0, zf1, zf0, zf1), BIAS(5+l));
    aT = MFMA(AW(9+l), mkfrag(tf0, tf1, tf0, tf1), BIAS(9+l));
  }
  act_sp(aY, yh0, yh1, yl0, yl1);
  act_sig(aZ, zf0, zf1);
  act_sig(aT, tf0, tf1);
  s8v FyH = mkfrag(yh0, yh1, yh0, yh1);
  s8v FyL = mkfrag(yl0, yl1, 0u, 0u);
  s8v Fz  = mkfrag(zf0, zf1, zf0, zf1);
  s8v Ft  = mkfrag(tf0, tf1, tf0, tf1);

  // ---- x first block (xfb bias via C-init of first MFMA)
  f32x4 aX = MFMA(AW(12), Bx0, BIAS(12));
  aX = MFMA(AW(13), Byz, aX);
  aX = MFMA(AW(14), Bt0, aX);

  // ---- 3 x iterations
  u32 xh0, xh1, xl0, xl1;
#pragma unroll
  for (int i = 0; i < 3; ++i) {
    act_sp(aX, xh0, xh1, xl0, xl1);
    s8v ax = AW(15+5*i);
    aX = MFMA(ax, mkfrag(xh0, xh1, xh0, xh1), BIAS(13+i));
    aX = MFMA(ax, mkfrag(xl0, xl1, 0u, 0u), aX);
    aX = MFMA(AW(16+5*i), Bx0, aX);
    s8v axy = AW(17+5*i);
    aX = MFMA(axy, FyH, aX);
    aX = MFMA(axy, FyL, aX);
    aX = MFMA(AW(18+5*i), Fz, aX);
    aX = MFMA(AW(19+5*i), Ft, aX);
  }

  // ---- final linear (fb bias via C-init)
  act_sp(aX, xh0, xh1, xl0, xl1);
  s8v af = AW(30);
  f32x4 aO = MFMA(af, mkfrag(xh0, xh1, xh0, xh1), BIAS(16));
  aO = MFMA(af, mkfrag(xl0, xl1, 0u, 0u), aO);

  // ---- coalesced store via tiny LDS transpose (ch15 slot = dead pad)
  *(f32x4*)(owave + c*20 + 4*g) = aO;
  float* orow = outg + (size_t)T * 240;
#pragma unroll
  for (int jj = 0; jj < 4; ++jj) {
    int i = lane + 64*jj;
    if (i < 240) {
      int row = i / 15, ch = i - row*15;
      orow[i] = owave[row*20 + ch];
    }
  }
#undef AW
#undef BIAS
}

#define NWAVE 8
#define NT 2

__global__ __launch_bounds__(512, 6) void isnn_fwd(
    const float* __restrict__ x0g, const float* __restrict__ y0g,
    const float* __restrict__ z0g, const float* __restrict__ t0g,
    const u32* __restrict__ Abuf, const float* __restrict__ biasg,
    float* __restrict__ outg)
{
  __shared__ u32x4 wlds[NSLOT*64];          // 31 KiB weight frags (block-shared)
  __shared__ float blds[NBIAS*16];          // 1.0625 KiB bias table
  __shared__ float olds[NWAVE][NT][320];    // per-wave per-tile staging (20 KiB)

  const int tid  = threadIdx.x;
  const int lane = tid & 63;
  const int w    = tid >> 6;
  const int g    = lane >> 4;
  const int c    = lane & 15;

  const int T0 = (blockIdx.x * NWAVE + w) * NT;

  // ---- tile-0 inputs issued BEFORE the stage barrier (latency hidden)
  Pre p0 = load_in(x0g, y0g, z0g, t0g, T0, c, g);

  for (int i = tid; i < NSLOT*64; i += 512) wlds[i] = ((const u32x4*)Abuf)[i];
  for (int i = tid; i < NBIAS*16; i += 512) blds[i] = biasg[i];
  __syncthreads();

  const char* wbase = (const char*)wlds + lane * 16;
  const char* bbase = (const char*)blds + g * 16;

  // ---- tile-1 inputs issued here: latency hides under tile-0 compute
  Pre p1 = load_in(x0g, y0g, z0g, t0g, T0 + 1, c, g);

  // Two straight-line bodies, NO sched barrier between them: the
  // compiler is free to interleave body-1's independent chains into
  // body-0's transcendental/MFMA stalls (85-reg budget gives headroom).
  tile_body(p0, T0,     wbase, bbase, &olds[w][0][0], outg, lane, g, c);
  tile_body(p1, T0 + 1, wbase, bbase, &olds[w][1][0], outg, lane, g, c);
}

extern "C" void kernel_launch(void* const* d_in, const int* in_sizes, int n_in,
                              void* d_out, int out_size, void* d_ws, size_t ws_size,
                              hipStream_t stream) {
  P p;
  p.yW0 = (const float*)d_in[4];  p.yWs = (const float*)d_in[5];  p.yb  = (const float*)d_in[6];
  p.zW0 = (const float*)d_in[7];  p.zWs = (const float*)d_in[8];  p.zb  = (const float*)d_in[9];
  p.tW0 = (const float*)d_in[10]; p.tWs = (const float*)d_in[11]; p.tb  = (const float*)d_in[12];
  p.x0W = (const float*)d_in[13]; p.x0b = (const float*)d_in[14];
  p.y0W = (const float*)d_in[15]; p.y0b = (const float*)d_in[16];
  p.z0W = (const float*)d_in[17]; p.z0b = (const float*)d_in[18];
  p.t0W = (const float*)d_in[19]; p.t0b = (const float*)d_in[20];
  p.xWs = (const float*)d_in[21]; p.xb  = (const float*)d_in[22];
  p.xsW = (const float*)d_in[23]; p.xsb = (const float*)d_in[24];
  p.xyW = (const float*)d_in[25]; p.xyb = (const float*)d_in[26];
  p.xzW = (const float*)d_in[27]; p.xzb = (const float*)d_in[28];
  p.xtW = (const float*)d_in[29]; p.xtb = (const float*)d_in[30];
  p.fW  = (const float*)d_in[31]; p.fb  = (const float*)d_in[32];

  u32* Abuf = (u32*)d_ws;
  float* biasb = (float*)(Abuf + NSLOT*256);

  prep_kernel<<<8, 256, 0, stream>>>(p, Abuf, biasb);

  const float* x0 = (const float*)d_in[0];
  const float* y0 = (const float*)d_in[1];
  const float* z0 = (const float*)d_in[2];
  const float* t0 = (const float*)d_in[3];

  const int n = in_sizes[0] / 16;            // 1048576 rows
  const int blocks = n / (NWAVE * 16 * NT);  // 8 waves x 2 tiles x 16 rows = 4096
  isnn_fwd<<<blocks, 512, 0, stream>>>(x0, y0, z0, t0, Abuf, biasb, (float*)d_out);
}

// Round 18
// 110.345 us; speedup vs baseline: 5.1108x; 5.1108x over previous
//
#include <hip/hip_runtime.h>
#include <hip/hip_bf16.h>

typedef short s8v  __attribute__((ext_vector_type(8)));
typedef float f32x4 __attribute__((ext_vector_type(4)));
typedef unsigned int u32;
typedef u32 u32x4 __attribute__((ext_vector_type(4)));

#define NSLOT 31
#define NBIAS 17

// ---------- bf16 helpers (RNE) ----------
__device__ __forceinline__ unsigned short b16hi(float v) {
  unsigned int u = __float_as_uint(v);
  return (unsigned short)((u + 0x7FFFu + ((u >> 16) & 1u)) >> 16);
}
__device__ __forceinline__ float b16tof(unsigned short h) {
  return __uint_as_float(((unsigned int)h) << 16);
}
__device__ __forceinline__ unsigned short lobits(float w) {
  return b16hi(w - b16tof(b16hi(w)));
}
__device__ __forceinline__ float sp_stable(float v) {
  float ax = __builtin_fabsf(v);
  float e  = __expf(-ax);
  return fmaxf(v, 0.0f) + __logf(1.0f + e);
}

// =====================================================================
// PREP (R12 layout, verified): A-frags for D = W . act^T, biases zeroed
// out of the weight slots; exact-f32 bias table consumed as MFMA C-init.
// lane l: m = l&15, k = 4*(l>>4)+{0..3} (dw0,1) and 16+4*(l>>4)+{0..3} (dw2,3)
// =====================================================================
struct P {
  const float *yW0,*yWs,*yb,*zW0,*zWs,*zb,*tW0,*tWs,*tb;
  const float *x0W,*x0b,*y0W,*y0b,*z0W,*z0b,*t0W,*t0b;
  const float *xWs,*xb,*xsW,*xsb,*xyW,*xyb,*xzW,*xzb,*xtW,*xtb,*fW,*fb;
};

__device__ unsigned short pat15(const float* W, int k, int j, int sp) {
  if (k < 15)           { float v = W[j*15+k];      return b16hi(sp ? sp_stable(v) : v); }
  if (k >= 16 && k < 31){ float v = W[j*15+(k-16)]; return lobits(sp ? sp_stable(v) : v); }
  return 0;
}

__device__ unsigned short wA(int s, int k, int j, const P& p) {
  if (j > 14) return 0;
  if (s == 0) {
    if (k < 8)   return b16hi(sp_stable(p.yW0[j*8+k]));
    if (k < 16)  return lobits(sp_stable(p.yW0[j*8+(k-8)]));
    return 0;
  }
  if (s <= 3)  return pat15(p.yWs + (s-1)*225, k, j, 1);
  if (s == 4) {
    if (k < 8)   return b16hi(p.zW0[j*8+k]);
    if (k < 16)  return lobits(p.zW0[j*8+(k-8)]);
    return 0;
  }
  if (s <= 7)  return pat15(p.zWs + (s-5)*225, k, j, 0);
  if (s == 8) {
    if (k < 4)   return b16hi(sp_stable(p.tW0[j*4+k]));
    if (k < 8)   return lobits(sp_stable(p.tW0[j*4+(k-4)]));
    return 0;
  }
  if (s <= 11) return pat15(p.tWs + (s-9)*225, k, j, 1);
  if (s == 12) {
    if (k < 16) return b16hi(p.x0W[j*16+k]);
    return lobits(p.x0W[j*16+(k-16)]);
  }
  if (s == 13) {
    if (k < 8)  return b16hi(sp_stable(p.y0W[j*8+k]));
    if (k < 16) return b16hi(p.z0W[j*8+(k-8)]);
    if (k < 24) return lobits(sp_stable(p.y0W[j*8+(k-16)]));
    return lobits(p.z0W[j*8+(k-24)]);
  }
  if (s == 14) {
    if (k < 4)  return b16hi(sp_stable(p.t0W[j*4+k]));
    if (k < 8)  return lobits(sp_stable(p.t0W[j*4+(k-4)]));
    return 0;
  }
  if (s <= 29) {
    int i = (s-15)/5, r = (s-15)%5;
    if (r == 0) return pat15(p.xWs + i*225, k, j, 1);
    if (r == 1) {
      const float* W = p.xsW + i*240;
      if (k < 16) return b16hi(W[j*16+k]);
      return lobits(W[j*16+(k-16)]);
    }
    if (r == 2) return pat15(p.xyW + i*225, k, j, 1);
    if (r == 3) return pat15(p.xzW + i*225, k, j, 0);
    return pat15(p.xtW + i*225, k, j, 1);
  }
  return pat15(p.fW, k, j, 0);   // s == 30
}

__global__ void prep_kernel(P p, u32* Abuf, float* biasb) {
  const int tid = blockIdx.x * blockDim.x + threadIdx.x;
  const int str = gridDim.x * blockDim.x;
  for (int idx = tid; idx < NSLOT*256; idx += str) {
    int s = idx >> 8, rem = idx & 255, l = rem >> 2, d = rem & 3;
    int g = l >> 4, j = l & 15;
    int kb = (d < 2) ? (4*g + 2*d) : (16 + 4*g + 2*(d-2));
    u32 v0 = wA(s, kb,   j, p);
    u32 v1 = wA(s, kb+1, j, p);
    Abuf[idx] = v0 | (v1 << 16);
  }
  for (int idx = tid; idx < NBIAS*16; idx += str) {
    int b = idx >> 4, n = idx & 15;
    float v = 0.f;
    if (n < 15) {
      if (b < 4)        v = p.yb[b*15 + n];
      else if (b < 8)   v = p.zb[(b-4)*15 + n];
      else if (b < 12)  v = p.tb[(b-8)*15 + n];
      else if (b == 12) v = p.x0b[n] + p.y0b[n] + p.z0b[n] + p.t0b[n];
      else if (b < 16)  { int i = b - 13;
        v = p.xb[i*15+n] + p.xsb[i*15+n] + p.xyb[i*15+n]
          + p.xzb[i*15+n] + p.xtb[i*15+n]; }
      else              v = p.fb[n];
    }
    biasb[idx] = v;
  }
}

// =====================================================================
// MAIN: best-known configuration (R15): 1024-thread blocks, 16 waves
// share one 31 KiB weight image, ONE tile per wave, straight-line body,
// (1024,8).  Micro-fix from R16's clean half: input loads issued BEFORE
// the stage loop so HBM latency hides under weight staging.
// Closed ledger: 1-tile straight-line is the ONLY spill-free structure
// (R10/R12/R13/R17 all spill); ILP and TLP levers are exhausted;
// plateau ~121 us dispatch = 79% of the issue-bound floor (~96 us).
// =====================================================================
union FragU { u32x4 u; s8v s; };
__device__ __forceinline__ s8v mkfrag(u32 a, u32 b, u32 c, u32 d) {
  FragU f; f.u = u32x4{a, b, c, d}; return f.s;
}
__device__ __forceinline__ u32 pk(float lo, float hi) {
  union { __hip_bfloat162 h; u32 u; } cv;
  cv.h = __float22bfloat162_rn(float2{lo, hi});
  return cv.u;
}
__device__ __forceinline__ float lo16f(u32 u) { return __uint_as_float(u << 16); }
__device__ __forceinline__ float hi16f(u32 u) { return __uint_as_float(u & 0xFFFF0000u); }

#define MFMA(A,B,C) __builtin_amdgcn_mfma_f32_16x16x32_bf16((A),(B),(C),0,0,0)

__device__ __forceinline__ void act_sp(f32x4 a, u32& h0, u32& h1,
                                       u32& l0, u32& l1) {
  const f32x4 z4 = {0.f, 0.f, 0.f, 0.f};
  f32x4 ax = __builtin_elementwise_abs(a);
  f32x4 mx = __builtin_elementwise_max(a, z4);
  f32x4 nt = ax * -1.442695041f;
  f32x4 e;
  e[0] = __builtin_amdgcn_exp2f(nt[0]); e[1] = __builtin_amdgcn_exp2f(nt[1]);
  e[2] = __builtin_amdgcn_exp2f(nt[2]); e[3] = __builtin_amdgcn_exp2f(nt[3]);
  f32x4 op = e + 1.0f;
  f32x4 lg;
  lg[0] = __builtin_amdgcn_logf(op[0]); lg[1] = __builtin_amdgcn_logf(op[1]);
  lg[2] = __builtin_amdgcn_logf(op[2]); lg[3] = __builtin_amdgcn_logf(op[3]);
  f32x4 v = lg * 0.6931471806f + mx;
  h0 = pk(v[0], v[1]);
  h1 = pk(v[2], v[3]);
  l0 = pk(v[0] - lo16f(h0), v[1] - hi16f(h0));
  l1 = pk(v[2] - lo16f(h1), v[3] - hi16f(h1));
}
__device__ __forceinline__ void act_sig(f32x4 a, u32& d0, u32& d1) {
  f32x4 nt = a * -1.442695041f;
  f32x4 e;
  e[0] = __builtin_amdgcn_exp2f(nt[0]); e[1] = __builtin_amdgcn_exp2f(nt[1]);
  e[2] = __builtin_amdgcn_exp2f(nt[2]); e[3] = __builtin_amdgcn_exp2f(nt[3]);
  f32x4 op = e + 1.0f;
  float r0 = __builtin_amdgcn_rcpf(op[0]), r1 = __builtin_amdgcn_rcpf(op[1]);
  float r2 = __builtin_amdgcn_rcpf(op[2]), r3 = __builtin_amdgcn_rcpf(op[3]);
  d0 = pk(r0, r1);
  d1 = pk(r2, r3);
}

#define NWAVE 16

__global__ __launch_bounds__(1024, 8) void isnn_fwd(
    const float* __restrict__ x0g, const float* __restrict__ y0g,
    const float* __restrict__ z0g, const float* __restrict__ t0g,
    const u32* __restrict__ Abuf, const float* __restrict__ biasg,
    float* __restrict__ outg)
{
  __shared__ u32x4 wlds[NSLOT*64];        // 31 KiB weight frags (block-shared)
  __shared__ float blds[NBIAS*16];        // 1.0625 KiB bias table
  __shared__ float olds[NWAVE][320];      // per-wave out staging (20 KiB)

  const int tid  = threadIdx.x;
  const int lane = tid & 63;
  const int w    = tid >> 6;
  const int g    = lane >> 4;
  const int c    = lane & 15;

  const int T = blockIdx.x * NWAVE + w;    // one 16-row tile per wave

  // ---- inputs issued BEFORE staging: HBM latency hides under the stage
  float4 x4 = ((const float4*)x0g)[(size_t)(T*16 + c)*4 + g];
  float4 y4 = ((const float4*)y0g)[(size_t)(T*16 + c)*2 + (g & 1)];
  float4 z4 = ((const float4*)z0g)[(size_t)(T*16 + c)*2 + (g & 1)];
  float4 t4 = ((const float4*)t0g)[(size_t)(T*16 + c)];

  for (int i = tid; i < NSLOT*64; i += 1024) wlds[i] = ((const u32x4*)Abuf)[i];
  for (int i = tid; i < NBIAS*16; i += 1024) blds[i] = biasg[i];
  __syncthreads();

  const char* wbase = (const char*)wlds + lane * 16;
#define AW(s)   (*(const s8v*)(wbase + (s)*1024))
  const char* bbase = (const char*)blds + g * 16;
#define BIAS(s) (*(const f32x4*)(bbase + (s)*64))

  // ---- build input B-frags
  u32 dx0 = pk(x4.x, x4.y), dx1 = pk(x4.z, x4.w);
  u32 dy0 = pk(y4.x, y4.y), dy1 = pk(y4.z, y4.w);
  u32 dz0 = pk(z4.x, z4.y), dz1 = pk(z4.z, z4.w);
  u32 dt0 = pk(t4.x, t4.y), dt1 = pk(t4.z, t4.w);
  s8v Bx0 = mkfrag(dx0, dx1, dx0, dx1);
  s8v By0 = mkfrag(dy0, dy1, 0u, 0u);
  s8v Bz0 = mkfrag(dz0, dz1, 0u, 0u);
  s8v Bt0 = mkfrag((g < 2) ? dt0 : 0u, (g < 2) ? dt1 : 0u, 0u, 0u);
  u32 syz0 = (g < 2) ? dy0 : dz0, syz1 = (g < 2) ? dy1 : dz1;
  s8v Byz = mkfrag(syz0, syz1, syz0, syz1);

  // ---- towers layer 1 (bias = exact-f32 C-init)
  f32x4 aY = MFMA(AW(0), By0, BIAS(0));
  f32x4 aZ = MFMA(AW(4), Bz0, BIAS(4));
  f32x4 aT = MFMA(AW(8), Bt0, BIAS(8));

  // ---- towers layers 2..4
  u32 yh0, yh1, yl0, yl1, zf0, zf1, tf0, tf1;
#pragma unroll
  for (int l = 0; l < 3; ++l) {
    act_sp(aY, yh0, yh1, yl0, yl1);
    act_sig(aZ, zf0, zf1);
    act_sig(aT, tf0, tf1);
    s8v ay = AW(1+l);
    aY = MFMA(ay, mkfrag(yh0, yh1, yh0, yh1), BIAS(1+l));
    aY = MFMA(ay, mkfrag(yl0, yl1, 0u, 0u), aY);
    aZ = MFMA(AW(5+l), mkfrag(zf0, zf1, zf0, zf1), BIAS(5+l));
    aT = MFMA(AW(9+l), mkfrag(tf0, tf1, tf0, tf1), BIAS(9+l));
  }
  act_sp(aY, yh0, yh1, yl0, yl1);
  act_sig(aZ, zf0, zf1);
  act_sig(aT, tf0, tf1);
  s8v FyH = mkfrag(yh0, yh1, yh0, yh1);
  s8v FyL = mkfrag(yl0, yl1, 0u, 0u);
  s8v Fz  = mkfrag(zf0, zf1, zf0, zf1);
  s8v Ft  = mkfrag(tf0, tf1, tf0, tf1);

  // ---- x first block (xfb bias via C-init of first MFMA)
  f32x4 aX = MFMA(AW(12), Bx0, BIAS(12));
  aX = MFMA(AW(13), Byz, aX);
  aX = MFMA(AW(14), Bt0, aX);

  // ---- 3 x iterations
  u32 xh0, xh1, xl0, xl1;
#pragma unroll
  for (int i = 0; i < 3; ++i) {
    act_sp(aX, xh0, xh1, xl0, xl1);
    s8v ax = AW(15+5*i);
    aX = MFMA(ax, mkfrag(xh0, xh1, xh0, xh1), BIAS(13+i));
    aX = MFMA(ax, mkfrag(xl0, xl1, 0u, 0u), aX);
    aX = MFMA(AW(16+5*i), Bx0, aX);
    s8v axy = AW(17+5*i);
    aX = MFMA(axy, FyH, aX);
    aX = MFMA(axy, FyL, aX);
    aX = MFMA(AW(18+5*i), Fz, aX);
    aX = MFMA(AW(19+5*i), Ft, aX);
  }

  // ---- final linear (fb bias via C-init)
  act_sp(aX, xh0, xh1, xl0, xl1);
  s8v af = AW(30);
  f32x4 aO = MFMA(af, mkfrag(xh0, xh1, xh0, xh1), BIAS(16));
  aO = MFMA(af, mkfrag(xl0, xl1, 0u, 0u), aO);

  // ---- coalesced store via tiny LDS transpose (ch15 slot = dead pad)
  *(f32x4*)(&olds[w][c*20 + 4*g]) = aO;
  float* orow = outg + (size_t)T * 240;
#pragma unroll
  for (int jj = 0; jj < 4; ++jj) {
    int i = lane + 64*jj;
    if (i < 240) {
      int row = i / 15, ch = i - row*15;
      orow[i] = olds[w][row*20 + ch];
    }
  }
#undef AW
#undef BIAS
}

extern "C" void kernel_launch(void* const* d_in, const int* in_sizes, int n_in,
                              void* d_out, int out_size, void* d_ws, size_t ws_size,
                              hipStream_t stream) {
  P p;
  p.yW0 = (const float*)d_in[4];  p.yWs = (const float*)d_in[5];  p.yb  = (const float*)d_in[6];
  p.zW0 = (const float*)d_in[7];  p.zWs = (const float*)d_in[8];  p.zb  = (const float*)d_in[9];
  p.tW0 = (const float*)d_in[10]; p.tWs = (const float*)d_in[11]; p.tb  = (const float*)d_in[12];
  p.x0W = (const float*)d_in[13]; p.x0b = (const float*)d_in[14];
  p.y0W = (const float*)d_in[15]; p.y0b = (const float*)d_in[16];
  p.z0W = (const float*)d_in[17]; p.z0b = (const float*)d_in[18];
  p.t0W = (const float*)d_in[19]; p.t0b = (const float*)d_in[20];
  p.xWs = (const float*)d_in[21]; p.xb  = (const float*)d_in[22];
  p.xsW = (const float*)d_in[23]; p.xsb = (const float*)d_in[24];
  p.xyW = (const float*)d_in[25]; p.xyb = (const float*)d_in[26];
  p.xzW = (const float*)d_in[27]; p.xzb = (const float*)d_in[28];
  p.xtW = (const float*)d_in[29]; p.xtb = (const float*)d_in[30];
  p.fW  = (const float*)d_in[31]; p.fb  = (const float*)d_in[32];

  u32* Abuf = (u32*)d_ws;
  float* biasb = (float*)(Abuf + NSLOT*256);

  prep_kernel<<<8, 256, 0, stream>>>(p, Abuf, biasb);

  const float* x0 = (const float*)d_in[0];
  const float* y0 = (const float*)d_in[1];
  const float* z0 = (const float*)d_in[2];
  const float* t0 = (const float*)d_in[3];

  const int n = in_sizes[0] / 16;          // 1048576 rows
  const int blocks = n / (NWAVE * 16);     // 16 waves x 1 tile x 16 rows = 4096
  isnn_fwd<<<blocks, 1024, 0, stream>>>(x0, y0, z0, t0, Abuf, biasb, (float*)d_out);
}

// Round 20
// 109.925 us; speedup vs baseline: 5.1303x; 1.0038x over previous
//
#include <hip/hip_runtime.h>
#include <hip/hip_bf16.h>

typedef short s8v  __attribute__((ext_vector_type(8)));
typedef float f32x4 __attribute__((ext_vector_type(4)));
typedef unsigned int u32;
typedef u32 u32x4 __attribute__((ext_vector_type(4)));

#define NSLOT 31
#define NBIAS 17

// ---------- bf16 helpers (RNE) ----------
__device__ __forceinline__ unsigned short b16hi(float v) {
  unsigned int u = __float_as_uint(v);
  return (unsigned short)((u + 0x7FFFu + ((u >> 16) & 1u)) >> 16);
}
__device__ __forceinline__ float b16tof(unsigned short h) {
  return __uint_as_float(((unsigned int)h) << 16);
}
__device__ __forceinline__ unsigned short lobits(float w) {
  return b16hi(w - b16tof(b16hi(w)));
}
__device__ __forceinline__ float sp_stable(float v) {
  float ax = __builtin_fabsf(v);
  float e  = __expf(-ax);
  return fmaxf(v, 0.0f) + __logf(1.0f + e);
}

// =====================================================================
// PREP (R12 layout, verified, UNCHANGED): A-frags for D = W . act^T,
// biases zeroed out of weight slots; exact-f32 bias table as MFMA C-init.
// lane l: m = l&15, k = 4*(l>>4)+{0..3} (dw0,1) and 16+4*(l>>4)+{0..3} (dw2,3)
// =====================================================================
struct P {
  const float *yW0,*yWs,*yb,*zW0,*zWs,*zb,*tW0,*tWs,*tb;
  const float *x0W,*x0b,*y0W,*y0b,*z0W,*z0b,*t0W,*t0b;
  const float *xWs,*xb,*xsW,*xsb,*xyW,*xyb,*xzW,*xzb,*xtW,*xtb,*fW,*fb;
};

__device__ unsigned short pat15(const float* W, int k, int j, int sp) {
  if (k < 15)           { float v = W[j*15+k];      return b16hi(sp ? sp_stable(v) : v); }
  if (k >= 16 && k < 31){ float v = W[j*15+(k-16)]; return lobits(sp ? sp_stable(v) : v); }
  return 0;
}

__device__ unsigned short wA(int s, int k, int j, const P& p) {
  if (j > 14) return 0;
  if (s == 0) {
    if (k < 8)   return b16hi(sp_stable(p.yW0[j*8+k]));
    if (k < 16)  return lobits(sp_stable(p.yW0[j*8+(k-8)]));
    return 0;
  }
  if (s <= 3)  return pat15(p.yWs + (s-1)*225, k, j, 1);
  if (s == 4) {
    if (k < 8)   return b16hi(p.zW0[j*8+k]);
    if (k < 16)  return lobits(p.zW0[j*8+(k-8)]);
    return 0;
  }
  if (s <= 7)  return pat15(p.zWs + (s-5)*225, k, j, 0);
  if (s == 8) {
    if (k < 4)   return b16hi(sp_stable(p.tW0[j*4+k]));
    if (k < 8)   return lobits(sp_stable(p.tW0[j*4+(k-4)]));
    return 0;
  }
  if (s <= 11) return pat15(p.tWs + (s-9)*225, k, j, 1);
  if (s == 12) {
    if (k < 16) return b16hi(p.x0W[j*16+k]);
    return lobits(p.x0W[j*16+(k-16)]);
  }
  if (s == 13) {
    if (k < 8)  return b16hi(sp_stable(p.y0W[j*8+k]));
    if (k < 16) return b16hi(p.z0W[j*8+(k-8)]);
    if (k < 24) return lobits(sp_stable(p.y0W[j*8+(k-16)]));
    return lobits(p.z0W[j*8+(k-24)]);
  }
  if (s == 14) {
    if (k < 4)  return b16hi(sp_stable(p.t0W[j*4+k]));
    if (k < 8)  return lobits(sp_stable(p.t0W[j*4+(k-4)]));
    return 0;
  }
  if (s <= 29) {
    int i = (s-15)/5, r = (s-15)%5;
    if (r == 0) return pat15(p.xWs + i*225, k, j, 1);
    if (r == 1) {
      const float* W = p.xsW + i*240;
      if (k < 16) return b16hi(W[j*16+k]);
      return lobits(W[j*16+(k-16)]);
    }
    if (r == 2) return pat15(p.xyW + i*225, k, j, 1);
    if (r == 3) return pat15(p.xzW + i*225, k, j, 0);
    return pat15(p.xtW + i*225, k, j, 1);
  }
  return pat15(p.fW, k, j, 0);   // s == 30
}

__global__ void prep_kernel(P p, u32* Abuf, float* biasb) {
  const int tid = blockIdx.x * blockDim.x + threadIdx.x;
  const int str = gridDim.x * blockDim.x;
  for (int idx = tid; idx < NSLOT*256; idx += str) {
    int s = idx >> 8, rem = idx & 255, l = rem >> 2, d = rem & 3;
    int g = l >> 4, j = l & 15;
    int kb = (d < 2) ? (4*g + 2*d) : (16 + 4*g + 2*(d-2));
    u32 v0 = wA(s, kb,   j, p);
    u32 v1 = wA(s, kb+1, j, p);
    Abuf[idx] = v0 | (v1 << 16);
  }
  for (int idx = tid; idx < NBIAS*16; idx += str) {
    int b = idx >> 4, n = idx & 15;
    float v = 0.f;
    if (n < 15) {
      if (b < 4)        v = p.yb[b*15 + n];
      else if (b < 8)   v = p.zb[(b-4)*15 + n];
      else if (b < 12)  v = p.tb[(b-8)*15 + n];
      else if (b == 12) v = p.x0b[n] + p.y0b[n] + p.z0b[n] + p.t0b[n];
      else if (b < 16)  { int i = b - 13;
        v = p.xb[i*15+n] + p.xsb[i*15+n] + p.xyb[i*15+n]
          + p.xzb[i*15+n] + p.xtb[i*15+n]; }
      else              v = p.fb[n];
    }
    biasb[idx] = v;
  }
}

// =====================================================================
// MAIN: R18's proven body/weight-image, at 512-thread blocks with LDS
// trimmed to 40512 B (<= 40960) -> 4 blocks/CU = 32 waves/CU and 4-way
// block desync per CU (attacks phase-locking at VALUBusy 79%).
// Only change vs R18: output staging is exact [16][15] layout — lane
// writes 4 predicated scalar ds_writes (ch 4g+r, ch<15), read side is
// a direct olds[i] -> orow[i] copy.  R19's two failed mechanisms
// (half-slot frags, two-pass staging) are NOT used.
// Anti-spill ledger: 1-tile straight-line body only.
// =====================================================================
union FragU { u32x4 u; s8v s; };
__device__ __forceinline__ s8v mkfrag(u32 a, u32 b, u32 c, u32 d) {
  FragU f; f.u = u32x4{a, b, c, d}; return f.s;
}
__device__ __forceinline__ u32 pk(float lo, float hi) {
  union { __hip_bfloat162 h; u32 u; } cv;
  cv.h = __float22bfloat162_rn(float2{lo, hi});
  return cv.u;
}
__device__ __forceinline__ float lo16f(u32 u) { return __uint_as_float(u << 16); }
__device__ __forceinline__ float hi16f(u32 u) { return __uint_as_float(u & 0xFFFF0000u); }

#define MFMA(A,B,C) __builtin_amdgcn_mfma_f32_16x16x32_bf16((A),(B),(C),0,0,0)

__device__ __forceinline__ void act_sp(f32x4 a, u32& h0, u32& h1,
                                       u32& l0, u32& l1) {
  const f32x4 z4 = {0.f, 0.f, 0.f, 0.f};
  f32x4 ax = __builtin_elementwise_abs(a);
  f32x4 mx = __builtin_elementwise_max(a, z4);
  f32x4 nt = ax * -1.442695041f;
  f32x4 e;
  e[0] = __builtin_amdgcn_exp2f(nt[0]); e[1] = __builtin_amdgcn_exp2f(nt[1]);
  e[2] = __builtin_amdgcn_exp2f(nt[2]); e[3] = __builtin_amdgcn_exp2f(nt[3]);
  f32x4 op = e + 1.0f;
  f32x4 lg;
  lg[0] = __builtin_amdgcn_logf(op[0]); lg[1] = __builtin_amdgcn_logf(op[1]);
  lg[2] = __builtin_amdgcn_logf(op[2]); lg[3] = __builtin_amdgcn_logf(op[3]);
  f32x4 v = lg * 0.6931471806f + mx;
  h0 = pk(v[0], v[1]);
  h1 = pk(v[2], v[3]);
  l0 = pk(v[0] - lo16f(h0), v[1] - hi16f(h0));
  l1 = pk(v[2] - lo16f(h1), v[3] - hi16f(h1));
}
__device__ __forceinline__ void act_sig(f32x4 a, u32& d0, u32& d1) {
  f32x4 nt = a * -1.442695041f;
  f32x4 e;
  e[0] = __builtin_amdgcn_exp2f(nt[0]); e[1] = __builtin_amdgcn_exp2f(nt[1]);
  e[2] = __builtin_amdgcn_exp2f(nt[2]); e[3] = __builtin_amdgcn_exp2f(nt[3]);
  f32x4 op = e + 1.0f;
  float r0 = __builtin_amdgcn_rcpf(op[0]), r1 = __builtin_amdgcn_rcpf(op[1]);
  float r2 = __builtin_amdgcn_rcpf(op[2]), r3 = __builtin_amdgcn_rcpf(op[3]);
  d0 = pk(r0, r1);
  d1 = pk(r2, r3);
}

#define NWAVE 8

__global__ __launch_bounds__(512, 8) void isnn_fwd(
    const float* __restrict__ x0g, const float* __restrict__ y0g,
    const float* __restrict__ z0g, const float* __restrict__ t0g,
    const u32* __restrict__ Abuf, const float* __restrict__ biasg,
    float* __restrict__ outg)
{
  __shared__ u32x4 wlds[NSLOT*64];        // 31744 B weight frags (full, proven)
  __shared__ float blds[NBIAS*16];        //  1088 B bias table
  __shared__ float olds[NWAVE][240];      //  7680 B out staging, [16][15] exact
                                          //  total 40512 B -> 4 blocks/CU

  const int tid  = threadIdx.x;
  const int lane = tid & 63;
  const int w    = tid >> 6;
  const int g    = lane >> 4;
  const int c    = lane & 15;

  const int T = blockIdx.x * NWAVE + w;    // one 16-row tile per wave

  // ---- inputs issued BEFORE staging: HBM latency hides under the stage
  float4 x4 = ((const float4*)x0g)[(size_t)(T*16 + c)*4 + g];
  float4 y4 = ((const float4*)y0g)[(size_t)(T*16 + c)*2 + (g & 1)];
  float4 z4 = ((const float4*)z0g)[(size_t)(T*16 + c)*2 + (g & 1)];
  float4 t4 = ((const float4*)t0g)[(size_t)(T*16 + c)];

  for (int i = tid; i < NSLOT*64; i += 512) wlds[i] = ((const u32x4*)Abuf)[i];
  for (int i = tid; i < NBIAS*16; i += 512) blds[i] = biasg[i];
  __syncthreads();

  const char* wbase = (const char*)wlds + lane * 16;
#define AW(s)   (*(const s8v*)(wbase + (s)*1024))
  const char* bbase = (const char*)blds + g * 16;
#define BIAS(s) (*(const f32x4*)(bbase + (s)*64))

  // ---- build input B-frags
  u32 dx0 = pk(x4.x, x4.y), dx1 = pk(x4.z, x4.w);
  u32 dy0 = pk(y4.x, y4.y), dy1 = pk(y4.z, y4.w);
  u32 dz0 = pk(z4.x, z4.y), dz1 = pk(z4.z, z4.w);
  u32 dt0 = pk(t4.x, t4.y), dt1 = pk(t4.z, t4.w);
  s8v Bx0 = mkfrag(dx0, dx1, dx0, dx1);
  s8v By0 = mkfrag(dy0, dy1, 0u, 0u);
  s8v Bz0 = mkfrag(dz0, dz1, 0u, 0u);
  s8v Bt0 = mkfrag((g < 2) ? dt0 : 0u, (g < 2) ? dt1 : 0u, 0u, 0u);
  u32 syz0 = (g < 2) ? dy0 : dz0, syz1 = (g < 2) ? dy1 : dz1;
  s8v Byz = mkfrag(syz0, syz1, syz0, syz1);

  // ---- towers layer 1 (bias = exact-f32 C-init)
  f32x4 aY = MFMA(AW(0), By0, BIAS(0));
  f32x4 aZ = MFMA(AW(4), Bz0, BIAS(4));
  f32x4 aT = MFMA(AW(8), Bt0, BIAS(8));

  // ---- towers layers 2..4
  u32 yh0, yh1, yl0, yl1, zf0, zf1, tf0, tf1;
#pragma unroll
  for (int l = 0; l < 3; ++l) {
    act_sp(aY, yh0, yh1, yl0, yl1);
    act_sig(aZ, zf0, zf1);
    act_sig(aT, tf0, tf1);
    s8v ay = AW(1+l);
    aY = MFMA(ay, mkfrag(yh0, yh1, yh0, yh1), BIAS(1+l));
    aY = MFMA(ay, mkfrag(yl0, yl1, 0u, 0u), aY);
    aZ = MFMA(AW(5+l), mkfrag(zf0, zf1, zf0, zf1), BIAS(5+l));
    aT = MFMA(AW(9+l), mkfrag(tf0, tf1, tf0, tf1), BIAS(9+l));
  }
  act_sp(aY, yh0, yh1, yl0, yl1);
  act_sig(aZ, zf0, zf1);
  act_sig(aT, tf0, tf1);
  s8v FyH = mkfrag(yh0, yh1, yh0, yh1);
  s8v FyL = mkfrag(yl0, yl1, 0u, 0u);
  s8v Fz  = mkfrag(zf0, zf1, zf0, zf1);
  s8v Ft  = mkfrag(tf0, tf1, tf0, tf1);

  // ---- x first block (xfb bias via C-init of first MFMA)
  f32x4 aX = MFMA(AW(12), Bx0, BIAS(12));
  aX = MFMA(AW(13), Byz, aX);
  aX = MFMA(AW(14), Bt0, aX);

  // ---- 3 x iterations
  u32 xh0, xh1, xl0, xl1;
#pragma unroll
  for (int i = 0; i < 3; ++i) {
    act_sp(aX, xh0, xh1, xl0, xl1);
    s8v ax = AW(15+5*i);
    aX = MFMA(ax, mkfrag(xh0, xh1, xh0, xh1), BIAS(13+i));
    aX = MFMA(ax, mkfrag(xl0, xl1, 0u, 0u), aX);
    aX = MFMA(AW(16+5*i), Bx0, aX);
    s8v axy = AW(17+5*i);
    aX = MFMA(axy, FyH, aX);
    aX = MFMA(axy, FyL, aX);
    aX = MFMA(AW(18+5*i), Fz, aX);
    aX = MFMA(AW(19+5*i), Ft, aX);
  }

  // ---- final linear (fb bias via C-init)
  act_sp(aX, xh0, xh1, xl0, xl1);
  s8v af = AW(30);
  f32x4 aO = MFMA(af, mkfrag(xh0, xh1, xh0, xh1), BIAS(16));
  aO = MFMA(af, mkfrag(xl0, xl1, 0u, 0u), aO);

  // ---- coalesced store via [16][15]-exact LDS staging:
  // lane (g,c) owns channels 4g..4g+3 of row c; ch 15 masked out.
  float* ow = &olds[w][0];
#pragma unroll
  for (int r = 0; r < 4; ++r) {
    int ch = 4*g + r;
    if (ch < 15) ow[c*15 + ch] = aO[r];
  }
  float* orow = outg + (size_t)T * 240;
#pragma unroll
  for (int jj = 0; jj < 4; ++jj) {
    int i = lane + 64*jj;
    if (i < 240) orow[i] = ow[i];   // direct copy: staging layout == output
  }
#undef AW
#undef BIAS
}

extern "C" void kernel_launch(void* const* d_in, const int* in_sizes, int n_in,
                              void* d_out, int out_size, void* d_ws, size_t ws_size,
                              hipStream_t stream) {
  P p;
  p.yW0 = (const float*)d_in[4];  p.yWs = (const float*)d_in[5];  p.yb  = (const float*)d_in[6];
  p.zW0 = (const float*)d_in[7];  p.zWs = (const float*)d_in[8];  p.zb  = (const float*)d_in[9];
  p.tW0 = (const float*)d_in[10]; p.tWs = (const float*)d_in[11]; p.tb  = (const float*)d_in[12];
  p.x0W = (const float*)d_in[13]; p.x0b = (const float*)d_in[14];
  p.y0W = (const float*)d_in[15]; p.y0b = (const float*)d_in[16];
  p.z0W = (const float*)d_in[17]; p.z0b = (const float*)d_in[18];
  p.t0W = (const float*)d_in[19]; p.t0b = (const float*)d_in[20];
  p.xWs = (const float*)d_in[21]; p.xb  = (const float*)d_in[22];
  p.xsW = (const float*)d_in[23]; p.xsb = (const float*)d_in[24];
  p.xyW = (const float*)d_in[25]; p.xyb = (const float*)d_in[26];
  p.xzW = (const float*)d_in[27]; p.xzb = (const float*)d_in[28];
  p.xtW = (const float*)d_in[29]; p.xtb = (const float*)d_in[30];
  p.fW  = (const float*)d_in[31]; p.fb  = (const float*)d_in[32];

  u32* Abuf = (u32*)d_ws;
  float* biasb = (float*)(Abuf + NSLOT*256);

  prep_kernel<<<8, 256, 0, stream>>>(p, Abuf, biasb);

  const float* x0 = (const float*)d_in[0];
  const float* y0 = (const float*)d_in[1];
  const float* z0 = (const float*)d_in[2];
  const float* t0 = (const float*)d_in[3];

  const int n = in_sizes[0] / 16;          // 1048576 rows
  const int blocks = n / (NWAVE * 16);     // 8 waves x 1 tile x 16 rows = 8192
  isnn_fwd<<<blocks, 512, 0, stream>>>(x0, y0, z0, t0, Abuf, biasb, (float*)d_out);
}